// Round 1
// baseline (971.769 us; speedup 1.0000x reference)
//
#include <hip/hip_runtime.h>
#include <hip/hip_bf16.h>

#define M_DIM 8192
#define N_DIM 4096
#define K_DIM 4096
#define BM 128
#define BN 128
#define BK 64

typedef __bf16 bf16x8 __attribute__((ext_vector_type(8)));
typedef float  f32x4  __attribute__((ext_vector_type(4)));
typedef unsigned short u16x8 __attribute__((ext_vector_type(8)));

// async global->LDS, 16B per lane, dest = wave-uniform base + lane*16
#define ASYNC16(g, l)                                                          \
  __builtin_amdgcn_global_load_lds(                                            \
      (__attribute__((address_space(1))) void*)(g),                            \
      (__attribute__((address_space(3))) void*)(l), 16, 0, 0)

static __device__ __forceinline__ unsigned short f2bf(float f) {
  unsigned int u = __float_as_uint(f);
  u += 0x7fffu + ((u >> 16) & 1u);   // round-to-nearest-even
  return (unsigned short)(u >> 16);
}

// 8 fp32 -> 8 bf16 (RNE via HW cvt_pk) -> one ds_write_b128
static __device__ __forceinline__ void cvt8_store(unsigned short* dst,
                                                  float4 a, float4 b) {
  unsigned int p0, p1, p2, p3;
  asm("v_cvt_pk_bf16_f32 %0, %1, %2" : "=v"(p0) : "v"(a.x), "v"(a.y));
  asm("v_cvt_pk_bf16_f32 %0, %1, %2" : "=v"(p1) : "v"(a.z), "v"(a.w));
  asm("v_cvt_pk_bf16_f32 %0, %1, %2" : "=v"(p2) : "v"(b.x), "v"(b.y));
  asm("v_cvt_pk_bf16_f32 %0, %1, %2" : "=v"(p3) : "v"(b.z), "v"(b.w));
  uint4 v; v.x = p0; v.y = p1; v.z = p2; v.w = p3;
  *(uint4*)dst = v;
}

// ---- W build: one block per output row, binary search into sorted COO ------
__global__ __launch_bounds__(256) void sl_prep_w(
    const float* __restrict__ vals, const int* __restrict__ rows,
    const int* __restrict__ cols, unsigned short* __restrict__ W, int nnz) {
  const int b = blockIdx.x;
  __shared__ __align__(16) unsigned short rowbuf[K_DIM];  // 8 KB
  u16x8* rb8 = (u16x8*)rowbuf;
  u16x8 z = {};
  rb8[threadIdx.x] = z;
  rb8[256 + threadIdx.x] = z;
  __syncthreads();
  int l = 0, h = nnz;
  while (l < h) { int m = (l + h) >> 1; if (rows[m] < b) l = m + 1; else h = m; }
  const int s = l;
  h = nnz;
  while (l < h) { int m = (l + h) >> 1; if (rows[m] <= b) l = m + 1; else h = m; }
  const int e = l;
  for (int k = s + threadIdx.x; k < e; k += 256)
    rowbuf[cols[k]] = f2bf(vals[k]);
  __syncthreads();
  u16x8* dst = (u16x8*)(W + (size_t)b * K_DIM);
  dst[threadIdx.x] = rb8[threadIdx.x];
  dst[256 + threadIdx.x] = rb8[256 + threadIdx.x];
}

// ---- bf16 MFMA GEMM, fp32 A consumed directly ------------------------------
// C[m][n] = sum_k A[m,k]*B[n,k] + bias[n].  A fp32 [M,K] (= x), B bf16 [N,K].
// block 256 = 4 waves (2x2), wave computes 64x64.
// LDS layout (both tiles): logical 16B chunk l of row r lives at phys chunk
// l ^ (r&7)  -> conflict-free ds_read_b128 fragments.
//   B: global_load_lds with pre-swizzled GLOBAL column (linear LDS dest).
//   A: reg-staged: thread reads linear fp32 chunk (tid&7) of row (tid>>3)+32r,
//      converts via v_cvt_pk_bf16_f32, ds_write_b128 to phys chunk
//      (tid&7)^(row&7)  -- same layout, so the fragment reads are unchanged.
// Pipeline per K-step: [sync: tile ready] -> ds_read frags -> issue A loads
// (half 0) -> [sync: reads done] -> issue B ASYNC16 -> MFMA h=0 -> cvt+write
// half 0, load half 1 -> MFMA h=1 -> cvt+write half 1.  Barrier's implicit
// vmcnt/lgkmcnt drain guarantees the next tile is complete.
__global__ __launch_bounds__(256, 3) void sl_gemm_bias(
    const float* __restrict__ A,            // x fp32 [M,K]
    const unsigned short* __restrict__ B,   // W bf16 [N,K]
    const float* __restrict__ bias,
    float* __restrict__ C) {
  __shared__ __align__(16) unsigned short As[BM * BK]; // 16 KB
  __shared__ __align__(16) unsigned short Bs[BN * BK]; // 16 KB

  const int tid  = threadIdx.x;
  const int wave = tid >> 6;
  const int lane = tid & 63;

  // XCD-aware bijective swizzle (2048 blocks, 8 XCDs, chunk=256).
  // Within a chunk: N-tile fastest -> concurrent blocks on one XCD share the
  // (fat, fp32) A strips in L2.
  const int orig = blockIdx.y * (M_DIM / BM) + blockIdx.x;    // 0..2047
  const int swz  = (orig & 7) * ((M_DIM / BM) * (N_DIM / BN) / 8) + (orig >> 3);
  const int nt   = swz & (N_DIM / BN - 1);
  const int mt   = swz >> 5;                                  // /(N_DIM/BN)
  const int m0 = mt * BM;
  const int n0 = nt * BN;

  // --- staging addressing
  const int srow = tid >> 3;                         // 0..31 (rounds add 32)
  const int pc   = (tid & 7) ^ (srow & 7);           // phys 16B chunk in row
  const float* gA = A + (size_t)(m0 + srow) * K_DIM + (tid & 7) * 8; // linear
  const unsigned short* gB = B + (size_t)(n0 + srow) * K_DIM + pc * 8; // swz
  unsigned short* wA = As + (size_t)srow * BK + pc * 8;
  unsigned short* lB = Bs + (size_t)(wave * 64) * 8;
  const size_t GROW = (size_t)32 * K_DIM;   // 32 rows ahead in global (elems)
  const size_t LROW = (size_t)256 * 8;      // 256 chunks ahead in LDS (elems)
  const size_t WROW = (size_t)32 * BK;      // 32 rows ahead in As (elems)

  // --- fragment addressing
  const int wm   = (wave >> 1) * 64;
  const int wn   = (wave & 1) * 64;
  const int fm   = lane & 15;
  const int quad = lane >> 4;
  const int sw   = fm & 7;                 // row-dependent swizzle bits

  f32x4 acc[4][4] = {};

  // ---- prologue: stage tile 0
#pragma unroll
  for (int r = 0; r < 4; ++r) ASYNC16(gB + r * GROW, lB + r * LROW);
  {
    float4 a0 = *(const float4*)(gA);
    float4 a1 = *(const float4*)(gA + 4);
    float4 a2 = *(const float4*)(gA + GROW);
    float4 a3 = *(const float4*)(gA + GROW + 4);
    cvt8_store(wA, a0, a1);
    cvt8_store(wA + WROW, a2, a3);
    float4 a4 = *(const float4*)(gA + 2 * GROW);
    float4 a5 = *(const float4*)(gA + 2 * GROW + 4);
    float4 a6 = *(const float4*)(gA + 3 * GROW);
    float4 a7 = *(const float4*)(gA + 3 * GROW + 4);
    cvt8_store(wA + 2 * WROW, a4, a5);
    cvt8_store(wA + 3 * WROW, a6, a7);
  }
  gA += BK;
  gB += BK;

  for (int k0 = 0; k0 < K_DIM; k0 += BK) {
    __syncthreads();   // drains vmcnt (B DMA) + lgkmcnt (A ds_writes)

    bf16x8 af[4][2], bfr[4][2];
#pragma unroll
    for (int t = 0; t < 4; ++t) {
#pragma unroll
      for (int hh = 0; hh < 2; ++hh) {
        const int p = ((hh * 4 + quad) ^ sw) * 8;   // phys chunk * 8 elems
        af[t][hh]  = *(const bf16x8*)(As + (size_t)(wm + t * 16 + fm) * BK + p);
        bfr[t][hh] = *(const bf16x8*)(Bs + (size_t)(wn + t * 16 + fm) * BK + p);
      }
    }

    const bool more = (k0 + BK < K_DIM);
    float4 a0, a1, a2, a3;
    if (more) {            // pure global->reg, no LDS hazard: issue pre-barrier
      a0 = *(const float4*)(gA);
      a1 = *(const float4*)(gA + 4);
      a2 = *(const float4*)(gA + GROW);
      a3 = *(const float4*)(gA + GROW + 4);
    }
    __syncthreads();       // all waves done reading -> buffers reusable

    if (more) {
#pragma unroll
      for (int r = 0; r < 4; ++r) ASYNC16(gB + r * GROW, lB + r * LROW);
      gB += BK;
    }

    // MFMA half 0
#pragma unroll
    for (int tm = 0; tm < 4; ++tm)
#pragma unroll
      for (int tn = 0; tn < 4; ++tn)
        acc[tm][tn] = __builtin_amdgcn_mfma_f32_16x16x32_bf16(
            af[tm][0], bfr[tn][0], acc[tm][tn], 0, 0, 0);

    float4 a4, a5, a6, a7;
    if (more) {
      cvt8_store(wA, a0, a1);
      cvt8_store(wA + WROW, a2, a3);
      a4 = *(const float4*)(gA + 2 * GROW);
      a5 = *(const float4*)(gA + 2 * GROW + 4);
      a6 = *(const float4*)(gA + 3 * GROW);
      a7 = *(const float4*)(gA + 3 * GROW + 4);
    }

    // MFMA half 1
#pragma unroll
    for (int tm = 0; tm < 4; ++tm)
#pragma unroll
      for (int tn = 0; tn < 4; ++tn)
        acc[tm][tn] = __builtin_amdgcn_mfma_f32_16x16x32_bf16(
            af[tm][1], bfr[tn][1], acc[tm][tn], 0, 0, 0);

    if (more) {
      cvt8_store(wA + 2 * WROW, a4, a5);
      cvt8_store(wA + 3 * WROW, a6, a7);
      gA += BK;
    }
  }

  // --- epilogue: D row = A-index (quad*4+reg), col = B-index (lane&15)
  float bv[4];
#pragma unroll
  for (int tn = 0; tn < 4; ++tn) bv[tn] = bias[n0 + wn + tn * 16 + fm];

#pragma unroll
  for (int tm = 0; tm < 4; ++tm) {
    const int mbase = m0 + wm + tm * 16 + quad * 4;
#pragma unroll
    for (int tn = 0; tn < 4; ++tn) {
      const int n = n0 + wn + tn * 16 + fm;
      float* p = C + (size_t)mbase * N_DIM + n;
#pragma unroll
      for (int r = 0; r < 4; ++r)
        __builtin_nontemporal_store(acc[tm][tn][r] + bv[tn], p + (size_t)r * N_DIM);
    }
  }
}

// ---- fallback (only if workspace too small): naive fp32 SpMM ----------------
__global__ void sl_naive(const float* __restrict__ x, const float* __restrict__ vals,
                         const int* __restrict__ rows, const int* __restrict__ cols,
                         const float* __restrict__ bias, float* __restrict__ out,
                         int nnz) {
  const int o = blockIdx.x;
  int l = 0, h = nnz;
  while (l < h) { int m = (l + h) >> 1; if (rows[m] < o) l = m + 1; else h = m; }
  const int s = l;
  h = nnz;
  while (l < h) { int m = (l + h) >> 1; if (rows[m] <= o) l = m + 1; else h = m; }
  const int e = l;
  const float bv = bias[o];
  for (int b = threadIdx.x; b < M_DIM; b += blockDim.x) {
    float acc = bv;
    const float* xb = x + (size_t)b * K_DIM;
    for (int k = s; k < e; ++k) acc += vals[k] * xb[cols[k]];
    out[(size_t)b * N_DIM + o] = acc;
  }
}

extern "C" void kernel_launch(void* const* d_in, const int* in_sizes, int n_in,
                              void* d_out, int out_size, void* d_ws, size_t ws_size,
                              hipStream_t stream) {
  const float* x    = (const float*)d_in[0];
  const float* vals = (const float*)d_in[1];
  const int*   rows = (const int*)d_in[2];
  const int*   cols = (const int*)d_in[3];
  const float* bias = (const float*)d_in[4];
  float* out = (float*)d_out;
  const int nnz = in_sizes[1];

  const size_t w_bytes = (size_t)N_DIM * K_DIM * 2;  // 32 MiB

  if (ws_size >= w_bytes) {
    unsigned short* W = (unsigned short*)d_ws;
    sl_prep_w<<<N_DIM, 256, 0, stream>>>(vals, rows, cols, W, nnz);
    sl_gemm_bias<<<dim3(M_DIM / BM, N_DIM / BN), 256, 0, stream>>>(x, W, bias, out);
  } else {
    sl_naive<<<N_DIM, 256, 0, stream>>>(x, vals, rows, cols, bias, out, nnz);
  }
}

// Round 2
// 549.587 us; speedup vs baseline: 1.7682x; 1.7682x over previous
//
#include <hip/hip_runtime.h>
#include <hip/hip_bf16.h>

#define M_DIM 8192
#define N_DIM 4096
#define K_DIM 4096
#define BM 256
#define BN 128
#define BK 64
#define A_ELEMS (BM * BK)                       // 16384 bf16 = 32 KiB
#define B_ELEMS (BN * BK)                       // 8192  bf16 = 16 KiB
#define LDS_BYTES ((3 * (A_ELEMS + B_ELEMS)) * 2)  // 147456 = 144 KiB
#define NT_TILES (K_DIM / BK)                   // 64

typedef __bf16 bf16x8 __attribute__((ext_vector_type(8)));
typedef float  f32x4  __attribute__((ext_vector_type(4)));
typedef unsigned short u16x8 __attribute__((ext_vector_type(8)));

// async global->LDS, 16B per lane, dest = wave-uniform base + lane*16
#define ASYNC16(g, l)                                                          \
  __builtin_amdgcn_global_load_lds(                                            \
      (__attribute__((address_space(1))) void*)(g),                            \
      (__attribute__((address_space(3))) void*)(l), 16, 0, 0)

static __device__ __forceinline__ unsigned short f2bf(float f) {
  unsigned int u = __float_as_uint(f);
  u += 0x7fffu + ((u >> 16) & 1u);   // round-to-nearest-even
  return (unsigned short)(u >> 16);
}

// ---- fused prep: blocks [0,N) build W rows (binary search); rest convert x --
__global__ __launch_bounds__(256) void sl_prep_bs(
    const float4* __restrict__ x4, u16x8* __restrict__ xb,
    const float* __restrict__ vals, const int* __restrict__ rows,
    const int* __restrict__ cols, unsigned short* __restrict__ W, int nnz) {
  const int b = blockIdx.x;
  if (b < N_DIM) {
    __shared__ __align__(16) unsigned short rowbuf[K_DIM];   // 8 KB
    u16x8* rb8 = (u16x8*)rowbuf;
    u16x8 z = {};
    rb8[threadIdx.x] = z;
    rb8[256 + threadIdx.x] = z;
    __syncthreads();
    int l = 0, h = nnz;
    while (l < h) { int m = (l + h) >> 1; if (rows[m] < b) l = m + 1; else h = m; }
    const int s = l;
    h = nnz;
    while (l < h) { int m = (l + h) >> 1; if (rows[m] <= b) l = m + 1; else h = m; }
    const int e = l;
    for (int k = s + threadIdx.x; k < e; k += 256)
      rowbuf[cols[k]] = f2bf(vals[k]);
    __syncthreads();
    u16x8* dst = (u16x8*)(W + (size_t)b * K_DIM);
    dst[threadIdx.x] = rb8[threadIdx.x];
    dst[256 + threadIdx.x] = rb8[256 + threadIdx.x];
  } else {
    const int i = (b - N_DIM) * 256 + threadIdx.x;
    float4 a = x4[2 * i];
    float4 c = x4[2 * i + 1];
    u16x8 o;
    o[0] = f2bf(a.x); o[1] = f2bf(a.y); o[2] = f2bf(a.z); o[3] = f2bf(a.w);
    o[4] = f2bf(c.x); o[5] = f2bf(c.y); o[6] = f2bf(c.z); o[7] = f2bf(c.w);
    xb[i] = o;
  }
}

// ---- bf16 MFMA GEMM, ring-3 deep pipeline ----------------------------------
// C[m][n] = sum_k A[m,k]*B[n,k] + bias[n].  A,B bf16 row-major [.,K].
// Block tile 256x128, BK=64, 512 threads = 8 waves (2m x 4n), per-wave 128x32.
// LDS: 3-buffer ring per operand (144 KiB).  Tile t lives in buffer t%3.
// Loads for tile t+2 (6 ASYNC16/thread: A rounds 0-3, B rounds 0-1) are issued
// 2/2/1/1 across the 4 phases of tile t -- buffer (t+2)%3 == (t-1)%3 was fully
// consumed at the end of tile t-1, so the writes race nothing.  The ONLY vmem
// wait in the loop is vmcnt(6) at the end of phase 3 (drains tile t+1's 6
// loads; tile t+2's 6 stay in flight across the barrier -> T4 counted-vmcnt).
// Phase p=(msub,kk): 6 ds_read_b128 (XOR-chunk swizzle, conflict-free) ->
// raw s_barrier -> lgkmcnt(0)+sched_barrier (rule #18) -> setprio(1) ->
// 8 MFMA (4 tm x 2 tn) -> setprio(0) -> barrier.
__global__ __launch_bounds__(512, 2) void sl_gemm_bias(
    const unsigned short* __restrict__ A,   // xb bf16 [M,K]
    const unsigned short* __restrict__ B,   // W  bf16 [N,K]
    const float* __restrict__ bias,
    float* __restrict__ C) {
  extern __shared__ __align__(16) unsigned short lds[];
  unsigned short* As = lds;                    // 3 * A_ELEMS
  unsigned short* Bs = lds + 3 * A_ELEMS;      // 3 * B_ELEMS

  const int tid  = threadIdx.x;
  const int wave = tid >> 6;
  const int lane = tid & 63;

  // XCD-aware bijective swizzle (1024 blocks, 8 XCDs, 128/chunk).
  // nt fastest within chunk: the 32 concurrent CUs of one XCD share a single
  // 2 MB A-panel (L2-resident) and stream the 32 B-panels (L3-resident).
  const int orig = blockIdx.y * (M_DIM / BM) + blockIdx.x;    // 0..1023
  const int swz  = (orig & 7) * 128 + (orig >> 3);
  const int mt   = swz >> 5;                                  // 0..31
  const int nt   = swz & 31;                                  // 0..31
  const int m0 = mt * BM;
  const int n0 = nt * BN;

  // --- staging addressing: round r covers rows r*64 + (tid>>3); phys chunk
  //     tid&7 of row holds logical chunk (tid&7)^(row&7)  (pre-swizzled src)
  const int srow = tid >> 3;                            // 0..63
  const int scol = ((tid & 7) ^ (srow & 7)) * 8;        // swizzled bf16 col
  const unsigned short* gA = A + (size_t)(m0 + srow) * K_DIM + scol;
  const unsigned short* gB = B + (size_t)(n0 + srow) * K_DIM + scol;
  const size_t GROW = (size_t)64 * K_DIM;   // 64 rows ahead in global (elems)
  const int ldsw = wave * 64 * 8;           // wave-uniform chunk base (elems)

  // --- fragment addressing
  const int wm   = (wave >> 2) * 128;
  const int wn   = (wave & 3) * 32;
  const int fm   = lane & 15;
  const int quad = lane >> 4;
  int offA[8], offB[2], pk[2];
#pragma unroll
  for (int i = 0; i < 8; ++i) offA[i] = (wm + i * 16 + fm) * BK;
#pragma unroll
  for (int i = 0; i < 2; ++i) offB[i] = (wn + i * 16 + fm) * BK;
#pragma unroll
  for (int i = 0; i < 2; ++i) pk[i] = ((i * 4 + quad) ^ (fm & 7)) * 8;

  f32x4 acc[8][2] = {};

  // ---- prologue: stage tiles 0 and 1 (6 loads each, in tile order)
#pragma unroll
  for (int tt = 0; tt < 2; ++tt) {
#pragma unroll
    for (int r = 0; r < 4; ++r)
      ASYNC16(gA + tt * BK + r * GROW, As + tt * A_ELEMS + ldsw + r * 4096);
#pragma unroll
    for (int r = 0; r < 2; ++r)
      ASYNC16(gB + tt * BK + r * GROW, Bs + tt * B_ELEMS + ldsw + r * 4096);
  }
  gA += 2 * BK;   // now at tile-2 columns
  gB += 2 * BK;
  asm volatile("s_waitcnt vmcnt(6)" ::: "memory");   // tile 0 landed
  __builtin_amdgcn_sched_barrier(0);
  __builtin_amdgcn_s_barrier();

#define PHASE(MS, KK, STAGE_CODE, TAIL_CODE)                                   \
  {                                                                            \
    bf16x8 a0 = *(const bf16x8*)(Ac + offA[(MS)*4 + 0] + pk[KK]);              \
    bf16x8 a1 = *(const bf16x8*)(Ac + offA[(MS)*4 + 1] + pk[KK]);              \
    bf16x8 a2 = *(const bf16x8*)(Ac + offA[(MS)*4 + 2] + pk[KK]);              \
    bf16x8 a3 = *(const bf16x8*)(Ac + offA[(MS)*4 + 3] + pk[KK]);              \
    bf16x8 b0 = *(const bf16x8*)(Bc + offB[0] + pk[KK]);                       \
    bf16x8 b1 = *(const bf16x8*)(Bc + offB[1] + pk[KK]);                       \
    STAGE_CODE                                                                 \
    __builtin_amdgcn_s_barrier();                                              \
    asm volatile("s_waitcnt lgkmcnt(0)" ::: "memory");                         \
    __builtin_amdgcn_sched_barrier(0);                                         \
    __builtin_amdgcn_s_setprio(1);                                             \
    acc[(MS)*4+0][0] = __builtin_amdgcn_mfma_f32_16x16x32_bf16(a0, b0, acc[(MS)*4+0][0], 0, 0, 0); \
    acc[(MS)*4+0][1] = __builtin_amdgcn_mfma_f32_16x16x32_bf16(a0, b1, acc[(MS)*4+0][1], 0, 0, 0); \
    acc[(MS)*4+1][0] = __builtin_amdgcn_mfma_f32_16x16x32_bf16(a1, b0, acc[(MS)*4+1][0], 0, 0, 0); \
    acc[(MS)*4+1][1] = __builtin_amdgcn_mfma_f32_16x16x32_bf16(a1, b1, acc[(MS)*4+1][1], 0, 0, 0); \
    acc[(MS)*4+2][0] = __builtin_amdgcn_mfma_f32_16x16x32_bf16(a2, b0, acc[(MS)*4+2][0], 0, 0, 0); \
    acc[(MS)*4+2][1] = __builtin_amdgcn_mfma_f32_16x16x32_bf16(a2, b1, acc[(MS)*4+2][1], 0, 0, 0); \
    acc[(MS)*4+3][0] = __builtin_amdgcn_mfma_f32_16x16x32_bf16(a3, b0, acc[(MS)*4+3][0], 0, 0, 0); \
    acc[(MS)*4+3][1] = __builtin_amdgcn_mfma_f32_16x16x32_bf16(a3, b1, acc[(MS)*4+3][1], 0, 0, 0); \
    __builtin_amdgcn_s_setprio(0);                                             \
    TAIL_CODE                                                                  \
    __builtin_amdgcn_s_barrier();                                              \
  }

  int cur = 0, nxt = 2;
  for (int t = 0; t < NT_TILES; ++t) {
    const unsigned short* Ac = As + cur * A_ELEMS;
    const unsigned short* Bc = Bs + cur * B_ELEMS;
    unsigned short* Asn = As + nxt * A_ELEMS + ldsw;
    unsigned short* Bsn = Bs + nxt * B_ELEMS + ldsw;
    const bool more = (t < NT_TILES - 2);

    PHASE(0, 0,
          if (more) { ASYNC16(gA, Asn); ASYNC16(gA + GROW, Asn + 4096); }, )
    PHASE(0, 1,
          if (more) { ASYNC16(gA + 2 * GROW, Asn + 2 * 4096);
                      ASYNC16(gA + 3 * GROW, Asn + 3 * 4096); }, )
    PHASE(1, 0,
          if (more) { ASYNC16(gB, Bsn); }, )
    PHASE(1, 1,
          if (more) { ASYNC16(gB + GROW, Bsn + 4096); },
          if (more) {           // drain tile t+1's 6 loads; t+2's stay in flight
            asm volatile("s_waitcnt vmcnt(6)" ::: "memory");
            __builtin_amdgcn_sched_barrier(0);
          } else if (t == NT_TILES - 2) {   // last prefetch: full drain
            asm volatile("s_waitcnt vmcnt(0)" ::: "memory");
            __builtin_amdgcn_sched_barrier(0);
          } )

    if (more) { gA += BK; gB += BK; }
    cur = (cur == 2) ? 0 : cur + 1;
    nxt = (nxt == 2) ? 0 : nxt + 1;
  }
#undef PHASE

  // --- epilogue: D row = A-index (quad*4+reg), col = B-index (lane&15)
  float bv[2];
#pragma unroll
  for (int tn = 0; tn < 2; ++tn) bv[tn] = bias[n0 + wn + tn * 16 + fm];

#pragma unroll
  for (int tm = 0; tm < 8; ++tm) {
    const int mbase = m0 + wm + tm * 16 + quad * 4;
#pragma unroll
    for (int tn = 0; tn < 2; ++tn) {
      const int n = n0 + wn + tn * 16 + fm;
      float* p = C + (size_t)mbase * N_DIM + n;
#pragma unroll
      for (int r = 0; r < 4; ++r)
        __builtin_nontemporal_store(acc[tm][tn][r] + bv[tn], p + (size_t)r * N_DIM);
    }
  }
}

// ---- fallback (only if workspace too small): naive fp32 SpMM ----------------
__global__ void sl_naive(const float* __restrict__ x, const float* __restrict__ vals,
                         const int* __restrict__ rows, const int* __restrict__ cols,
                         const float* __restrict__ bias, float* __restrict__ out,
                         int nnz) {
  const int o = blockIdx.x;
  int l = 0, h = nnz;
  while (l < h) { int m = (l + h) >> 1; if (rows[m] < o) l = m + 1; else h = m; }
  const int s = l;
  h = nnz;
  while (l < h) { int m = (l + h) >> 1; if (rows[m] <= o) l = m + 1; else h = m; }
  const int e = l;
  const float bv = bias[o];
  for (int b = threadIdx.x; b < M_DIM; b += blockDim.x) {
    float acc = bv;
    const float* xb = x + (size_t)b * K_DIM;
    for (int k = s; k < e; ++k) acc += vals[k] * xb[cols[k]];
    out[(size_t)b * N_DIM + o] = acc;
  }
}

extern "C" void kernel_launch(void* const* d_in, const int* in_sizes, int n_in,
                              void* d_out, int out_size, void* d_ws, size_t ws_size,
                              hipStream_t stream) {
  const float* x    = (const float*)d_in[0];
  const float* vals = (const float*)d_in[1];
  const int*   rows = (const int*)d_in[2];
  const int*   cols = (const int*)d_in[3];
  const float* bias = (const float*)d_in[4];
  float* out = (float*)d_out;
  const int nnz = in_sizes[1];

  const size_t xb_bytes = (size_t)M_DIM * K_DIM * 2;  // 64 MiB
  const size_t w_bytes  = (size_t)N_DIM * K_DIM * 2;  // 32 MiB
  const int cvt_blocks  = (M_DIM * K_DIM) / 8 / 256;  // 16384

  if (ws_size >= xb_bytes + w_bytes) {
    unsigned short* xb = (unsigned short*)d_ws;
    unsigned short* W  = (unsigned short*)((char*)d_ws + xb_bytes);

    static bool attr_done = false;
    if (!attr_done) {
      (void)hipFuncSetAttribute((const void*)sl_gemm_bias,
                                hipFuncAttributeMaxDynamicSharedMemorySize,
                                LDS_BYTES);
      attr_done = true;
    }

    sl_prep_bs<<<N_DIM + cvt_blocks, 256, 0, stream>>>(
        (const float4*)x, (u16x8*)xb, vals, rows, cols, W, nnz);
    sl_gemm_bias<<<dim3(M_DIM / BM, N_DIM / BN), 512, LDS_BYTES, stream>>>(
        xb, W, bias, out);
  } else {
    sl_naive<<<N_DIM, 256, 0, stream>>>(x, vals, rows, cols, bias, out, nnz);
  }
}

// Round 3
// 519.286 us; speedup vs baseline: 1.8714x; 1.0584x over previous
//
#include <hip/hip_runtime.h>
#include <hip/hip_bf16.h>

#define M_DIM 8192
#define N_DIM 4096
#define K_DIM 4096
#define BM 256
#define BN 256
#define BK 32
#define A_ELEMS (BM * BK)                        // 8192 bf16 = 16 KiB
#define B_ELEMS (BN * BK)                        // 8192 bf16 = 16 KiB
#define LDS_BYTES (3 * (A_ELEMS + B_ELEMS) * 2)  // 98304 = 96 KiB
#define NT_TILES (K_DIM / BK)                    // 128

typedef __bf16 bf16x8 __attribute__((ext_vector_type(8)));
typedef float  f32x4  __attribute__((ext_vector_type(4)));
typedef unsigned short u16x8 __attribute__((ext_vector_type(8)));

// async global->LDS, 16B per lane, dest = wave-uniform base + lane*16
#define ASYNC16(g, l)                                                          \
  __builtin_amdgcn_global_load_lds(                                            \
      (__attribute__((address_space(1))) void*)(g),                            \
      (__attribute__((address_space(3))) void*)(l), 16, 0, 0)

static __device__ __forceinline__ unsigned short f2bf(float f) {
  unsigned int u = __float_as_uint(f);
  u += 0x7fffu + ((u >> 16) & 1u);   // round-to-nearest-even
  return (unsigned short)(u >> 16);
}

// ---- fused prep: blocks [0,N) build W rows (binary search); rest convert x --
__global__ __launch_bounds__(256) void sl_prep_bs(
    const float4* __restrict__ x4, u16x8* __restrict__ xb,
    const float* __restrict__ vals, const int* __restrict__ rows,
    const int* __restrict__ cols, unsigned short* __restrict__ W, int nnz) {
  const int b = blockIdx.x;
  if (b < N_DIM) {
    __shared__ __align__(16) unsigned short rowbuf[K_DIM];   // 8 KB
    u16x8* rb8 = (u16x8*)rowbuf;
    u16x8 z = {};
    rb8[threadIdx.x] = z;
    rb8[256 + threadIdx.x] = z;
    __syncthreads();
    int l = 0, h = nnz;
    while (l < h) { int m = (l + h) >> 1; if (rows[m] < b) l = m + 1; else h = m; }
    const int s = l;
    h = nnz;
    while (l < h) { int m = (l + h) >> 1; if (rows[m] <= b) l = m + 1; else h = m; }
    const int e = l;
    for (int k = s + threadIdx.x; k < e; k += 256)
      rowbuf[cols[k]] = f2bf(vals[k]);
    __syncthreads();
    u16x8* dst = (u16x8*)(W + (size_t)b * K_DIM);
    dst[threadIdx.x] = rb8[threadIdx.x];
    dst[256 + threadIdx.x] = rb8[256 + threadIdx.x];
  } else {
    const int i = (b - N_DIM) * 256 + threadIdx.x;
    float4 a = x4[2 * i];
    float4 c = x4[2 * i + 1];
    u16x8 o;
    o[0] = f2bf(a.x); o[1] = f2bf(a.y); o[2] = f2bf(a.z); o[3] = f2bf(a.w);
    o[4] = f2bf(c.x); o[5] = f2bf(c.y); o[6] = f2bf(c.z); o[7] = f2bf(c.w);
    xb[i] = o;
  }
}

// ---- bf16 MFMA GEMM, ring-3 deep pipeline, 256x256 tile --------------------
// C[m][n] = sum_k A[m,k]*B[n,k] + bias[n].  A,B bf16 row-major [.,K].
// 512 threads = 8 waves (2m x 4n); per-wave output 128x64 -> reads/MFMA =
// 1/8 + 1/4 = 0.375 ds_read_b128 per MFMA (round-2's 128x32 waves were 0.75:
// LDS-BW-bound, MfmaUtil 36%).  BK=32, ring-3 LDS (96 KiB): tile t in buffer
// t%3; tile t+2's 4 loads/thread issued 2/2 across tile t's 2 phases (buffer
// (t+2)%3 was consumed at end of tile t-1); sole loop wait = vmcnt(4) at end
// of tile t (drains t+1, keeps t+2 in flight -> T4 counted-vmcnt).  Phase =
// ds_read frags -> stage -> barrier -> lgkmcnt(0)+sched_barrier (rule #18) ->
// setprio(1) -> 16 MFMA -> setprio(0) -> barrier.  B-frags read in phase 0,
// reused from registers in phase 1.
__global__ __launch_bounds__(512, 2) void sl_gemm_bias(
    const unsigned short* __restrict__ A,   // xb bf16 [M,K]
    const unsigned short* __restrict__ B,   // W  bf16 [N,K]
    const float* __restrict__ bias,
    float* __restrict__ C) {
  extern __shared__ __align__(16) unsigned short lds[];
  unsigned short* As = lds;                    // 3 * A_ELEMS
  unsigned short* Bs = lds + 3 * A_ELEMS;      // 3 * B_ELEMS

  const int tid  = threadIdx.x;
  const int wave = tid >> 6;
  const int lane = tid & 63;

  // XCD-aware bijective swizzle (512 blocks, 8 XCDs, 64/chunk), nt fastest:
  // concurrent CUs of one XCD share ~2 A-panels (4 MB, L2-resident); B (32 MB)
  // streams from L3 (whole working set 96 MB < 256 MB L3).
  const int orig = blockIdx.y * (M_DIM / BM) + blockIdx.x;    // 0..511
  const int swz  = (orig & 7) * 64 + (orig >> 3);
  const int mt   = swz >> 4;                                  // 0..31
  const int nt   = swz & 15;                                  // 0..15
  const int m0 = mt * BM;
  const int n0 = nt * BN;

  // --- staging: thread covers row (tid>>2)+128r, phys 16B chunk tid&3 holds
  //     logical chunk (tid&3)^(row&3)  (pre-swizzled global source)
  const int srow = tid >> 2;                            // 0..127
  const int scol = ((tid & 3) ^ (srow & 3)) * 8;        // swizzled bf16 col
  const unsigned short* gA = A + (size_t)(m0 + srow) * K_DIM + scol;
  const unsigned short* gB = B + (size_t)(n0 + srow) * K_DIM + scol;
  const size_t GROW = (size_t)128 * K_DIM;  // 128 rows ahead (elems)
  const int ldsw = wave * 512;              // wave-uniform chunk base (elems)

  // --- fragment addressing (per-wave 128x64: 8 m-frags x 4 n-frags)
  const int wm   = (wave >> 2) * 128;
  const int wn   = (wave & 3) * 64;
  const int fm   = lane & 15;
  const int quad = lane >> 4;
  const int pk   = (quad ^ (fm & 3)) * 8;   // phys chunk * 8 elems
  int offA[8], offB[4];
#pragma unroll
  for (int i = 0; i < 8; ++i) offA[i] = (wm + i * 16 + fm) * BK + pk;
#pragma unroll
  for (int j = 0; j < 4; ++j) offB[j] = (wn + j * 16 + fm) * BK + pk;

  f32x4 acc[8][4] = {};

  // ---- prologue: stage tiles 0 and 1 (4 loads each, tile order)
#pragma unroll
  for (int tt = 0; tt < 2; ++tt) {
    ASYNC16(gA + tt * BK,        As + tt * A_ELEMS + ldsw);
    ASYNC16(gA + tt * BK + GROW, As + tt * A_ELEMS + 4096 + ldsw);
    ASYNC16(gB + tt * BK,        Bs + tt * B_ELEMS + ldsw);
    ASYNC16(gB + tt * BK + GROW, Bs + tt * B_ELEMS + 4096 + ldsw);
  }
  gA += 2 * BK;
  gB += 2 * BK;
  asm volatile("s_waitcnt vmcnt(4)" ::: "memory");   // tile 0 landed
  __builtin_amdgcn_sched_barrier(0);
  __builtin_amdgcn_s_barrier();

  int cur = 0, nxt = 2;
  for (int t = 0; t < NT_TILES; ++t) {
    const unsigned short* Ac = As + cur * A_ELEMS;
    const unsigned short* Bc = Bs + cur * B_ELEMS;
    unsigned short* Asn = As + nxt * A_ELEMS + ldsw;
    unsigned short* Bsn = Bs + nxt * B_ELEMS + ldsw;
    const bool more = (t < NT_TILES - 2);

    // ---- phase 0: m-half 0 ------------------------------------------------
    bf16x8 a0 = *(const bf16x8*)(Ac + offA[0]);
    bf16x8 a1 = *(const bf16x8*)(Ac + offA[1]);
    bf16x8 a2 = *(const bf16x8*)(Ac + offA[2]);
    bf16x8 a3 = *(const bf16x8*)(Ac + offA[3]);
    bf16x8 b0 = *(const bf16x8*)(Bc + offB[0]);
    bf16x8 b1 = *(const bf16x8*)(Bc + offB[1]);
    bf16x8 b2 = *(const bf16x8*)(Bc + offB[2]);
    bf16x8 b3 = *(const bf16x8*)(Bc + offB[3]);
    if (more) {
      ASYNC16(gA, Asn);
      ASYNC16(gA + GROW, Asn + 4096);
    }
    __builtin_amdgcn_sched_barrier(0);
    __builtin_amdgcn_s_barrier();
    asm volatile("s_waitcnt lgkmcnt(0)" ::: "memory");
    __builtin_amdgcn_sched_barrier(0);
    __builtin_amdgcn_s_setprio(1);
#pragma unroll
    for (int j = 0; j < 4; ++j) {
      bf16x8 bj = (j == 0) ? b0 : (j == 1) ? b1 : (j == 2) ? b2 : b3;
      acc[0][j] = __builtin_amdgcn_mfma_f32_16x16x32_bf16(a0, bj, acc[0][j], 0, 0, 0);
      acc[1][j] = __builtin_amdgcn_mfma_f32_16x16x32_bf16(a1, bj, acc[1][j], 0, 0, 0);
      acc[2][j] = __builtin_amdgcn_mfma_f32_16x16x32_bf16(a2, bj, acc[2][j], 0, 0, 0);
      acc[3][j] = __builtin_amdgcn_mfma_f32_16x16x32_bf16(a3, bj, acc[3][j], 0, 0, 0);
    }
    __builtin_amdgcn_s_setprio(0);
    __builtin_amdgcn_s_barrier();

    // ---- phase 1: m-half 1 (B frags reused from registers) -----------------
    bf16x8 a4 = *(const bf16x8*)(Ac + offA[4]);
    bf16x8 a5 = *(const bf16x8*)(Ac + offA[5]);
    bf16x8 a6 = *(const bf16x8*)(Ac + offA[6]);
    bf16x8 a7 = *(const bf16x8*)(Ac + offA[7]);
    if (more) {
      ASYNC16(gB, Bsn);
      ASYNC16(gB + GROW, Bsn + 4096);
    }
    __builtin_amdgcn_sched_barrier(0);
    __builtin_amdgcn_s_barrier();
    asm volatile("s_waitcnt lgkmcnt(0)" ::: "memory");
    __builtin_amdgcn_sched_barrier(0);
    __builtin_amdgcn_s_setprio(1);
#pragma unroll
    for (int j = 0; j < 4; ++j) {
      bf16x8 bj = (j == 0) ? b0 : (j == 1) ? b1 : (j == 2) ? b2 : b3;
      acc[4][j] = __builtin_amdgcn_mfma_f32_16x16x32_bf16(a4, bj, acc[4][j], 0, 0, 0);
      acc[5][j] = __builtin_amdgcn_mfma_f32_16x16x32_bf16(a5, bj, acc[5][j], 0, 0, 0);
      acc[6][j] = __builtin_amdgcn_mfma_f32_16x16x32_bf16(a6, bj, acc[6][j], 0, 0, 0);
      acc[7][j] = __builtin_amdgcn_mfma_f32_16x16x32_bf16(a7, bj, acc[7][j], 0, 0, 0);
    }
    __builtin_amdgcn_s_setprio(0);
    if (more) {              // drain tile t+1's 4 loads; t+2's stay in flight
      asm volatile("s_waitcnt vmcnt(4)" ::: "memory");
      __builtin_amdgcn_sched_barrier(0);
    } else if (t == NT_TILES - 2) {   // last prefetch already issued: drain all
      asm volatile("s_waitcnt vmcnt(0)" ::: "memory");
      __builtin_amdgcn_sched_barrier(0);
    }
    __builtin_amdgcn_s_barrier();

    if (more) { gA += BK; gB += BK; }
    cur = (cur == 2) ? 0 : cur + 1;
    nxt = (nxt == 2) ? 0 : nxt + 1;
  }

  // --- epilogue: D row = A-index (quad*4+reg), col = B-index (lane&15)
  float bv[4];
#pragma unroll
  for (int tn = 0; tn < 4; ++tn) bv[tn] = bias[n0 + wn + tn * 16 + fm];

#pragma unroll
  for (int tm = 0; tm < 8; ++tm) {
    const int mbase = m0 + wm + tm * 16 + quad * 4;
#pragma unroll
    for (int tn = 0; tn < 4; ++tn) {
      const int n = n0 + wn + tn * 16 + fm;
      float* p = C + (size_t)mbase * N_DIM + n;
#pragma unroll
      for (int r = 0; r < 4; ++r)
        __builtin_nontemporal_store(acc[tm][tn][r] + bv[tn], p + (size_t)r * N_DIM);
    }
  }
}

// ---- fallback (only if workspace too small): naive fp32 SpMM ----------------
__global__ void sl_naive(const float* __restrict__ x, const float* __restrict__ vals,
                         const int* __restrict__ rows, const int* __restrict__ cols,
                         const float* __restrict__ bias, float* __restrict__ out,
                         int nnz) {
  const int o = blockIdx.x;
  int l = 0, h = nnz;
  while (l < h) { int m = (l + h) >> 1; if (rows[m] < o) l = m + 1; else h = m; }
  const int s = l;
  h = nnz;
  while (l < h) { int m = (l + h) >> 1; if (rows[m] <= o) l = m + 1; else h = m; }
  const int e = l;
  const float bv = bias[o];
  for (int b = threadIdx.x; b < M_DIM; b += blockDim.x) {
    float acc = bv;
    const float* xb = x + (size_t)b * K_DIM;
    for (int k = s; k < e; ++k) acc += vals[k] * xb[cols[k]];
    out[(size_t)b * N_DIM + o] = acc;
  }
}

extern "C" void kernel_launch(void* const* d_in, const int* in_sizes, int n_in,
                              void* d_out, int out_size, void* d_ws, size_t ws_size,
                              hipStream_t stream) {
  const float* x    = (const float*)d_in[0];
  const float* vals = (const float*)d_in[1];
  const int*   rows = (const int*)d_in[2];
  const int*   cols = (const int*)d_in[3];
  const float* bias = (const float*)d_in[4];
  float* out = (float*)d_out;
  const int nnz = in_sizes[1];

  const size_t xb_bytes = (size_t)M_DIM * K_DIM * 2;  // 64 MiB
  const size_t w_bytes  = (size_t)N_DIM * K_DIM * 2;  // 32 MiB
  const int cvt_blocks  = (M_DIM * K_DIM) / 8 / 256;  // 16384

  if (ws_size >= xb_bytes + w_bytes) {
    unsigned short* xb = (unsigned short*)d_ws;
    unsigned short* W  = (unsigned short*)((char*)d_ws + xb_bytes);

    static bool attr_done = false;
    if (!attr_done) {
      (void)hipFuncSetAttribute((const void*)sl_gemm_bias,
                                hipFuncAttributeMaxDynamicSharedMemorySize,
                                LDS_BYTES);
      attr_done = true;
    }

    sl_prep_bs<<<N_DIM + cvt_blocks, 256, 0, stream>>>(
        (const float4*)x, (u16x8*)xb, vals, rows, cols, W, nnz);
    sl_gemm_bias<<<dim3(M_DIM / BM, N_DIM / BN), 512, LDS_BYTES, stream>>>(
        xb, W, bias, out);
  } else {
    sl_naive<<<N_DIM, 256, 0, stream>>>(x, vals, rows, cols, bias, out, nnz);
  }
}

// Round 4
// 490.084 us; speedup vs baseline: 1.9829x; 1.0596x over previous
//
#include <hip/hip_runtime.h>
#include <hip/hip_bf16.h>

#define M_DIM 8192
#define N_DIM 4096
#define K_DIM 4096
#define BM 256
#define BN 256
#define BK 64
#define A_ELEMS (BM * BK)                        // 16384 bf16 = 32 KiB
#define B_ELEMS (BN * BK)                        // 16384 bf16 = 32 KiB
#define LDS_BYTES (2 * (A_ELEMS + B_ELEMS) * 2)  // 131072 = 128 KiB
#define NT_TILES (K_DIM / BK)                    // 64

typedef __bf16 bf16x8 __attribute__((ext_vector_type(8)));
typedef float  f32x4  __attribute__((ext_vector_type(4)));
typedef unsigned short u16x8 __attribute__((ext_vector_type(8)));

// async global->LDS, 16B per lane, dest = wave-uniform base + lane*16
#define ASYNC16(g, l)                                                          \
  __builtin_amdgcn_global_load_lds(                                            \
      (__attribute__((address_space(1))) void*)(g),                            \
      (__attribute__((address_space(3))) void*)(l), 16, 0, 0)

static __device__ __forceinline__ unsigned short f2bf(float f) {
  unsigned int u = __float_as_uint(f);
  u += 0x7fffu + ((u >> 16) & 1u);   // round-to-nearest-even
  return (unsigned short)(u >> 16);
}

// ---- fused prep: blocks [0,N) build W rows (binary search); rest convert x --
__global__ __launch_bounds__(256) void sl_prep_bs(
    const float4* __restrict__ x4, u16x8* __restrict__ xb,
    const float* __restrict__ vals, const int* __restrict__ rows,
    const int* __restrict__ cols, unsigned short* __restrict__ W, int nnz) {
  const int b = blockIdx.x;
  if (b < N_DIM) {
    __shared__ __align__(16) unsigned short rowbuf[K_DIM];   // 8 KB
    u16x8* rb8 = (u16x8*)rowbuf;
    u16x8 z = {};
    rb8[threadIdx.x] = z;
    rb8[256 + threadIdx.x] = z;
    __syncthreads();
    int l = 0, h = nnz;
    while (l < h) { int m = (l + h) >> 1; if (rows[m] < b) l = m + 1; else h = m; }
    const int s = l;
    h = nnz;
    while (l < h) { int m = (l + h) >> 1; if (rows[m] <= b) l = m + 1; else h = m; }
    const int e = l;
    for (int k = s + threadIdx.x; k < e; k += 256)
      rowbuf[cols[k]] = f2bf(vals[k]);
    __syncthreads();
    u16x8* dst = (u16x8*)(W + (size_t)b * K_DIM);
    dst[threadIdx.x] = rb8[threadIdx.x];
    dst[256 + threadIdx.x] = rb8[256 + threadIdx.x];
  } else {
    const int i = (b - N_DIM) * 256 + threadIdx.x;
    float4 a = x4[2 * i];
    float4 c = x4[2 * i + 1];
    u16x8 o;
    o[0] = f2bf(a.x); o[1] = f2bf(a.y); o[2] = f2bf(a.z); o[3] = f2bf(a.w);
    o[4] = f2bf(c.x); o[5] = f2bf(c.y); o[6] = f2bf(c.z); o[7] = f2bf(c.w);
    xb[i] = o;
  }
}

// ---- bf16 MFMA GEMM: 256x256 tile, BK=64, dbuf LDS, 4-phase schedule -------
// C[m][n] = sum_k A[m,k]*B[n,k] + bias[n].  A,B bf16 row-major [.,K].
// 512 threads = 8 waves (2m x 4n), per-wave output 128x64 -> reads/MFMA =
// 1/8 + 1/4 = 0.375 (round-3 insight).  BK=64 restores the conflict-free
// swizzle (round-3's BK=32 rows = 64 B = 16 banks -> only row parity reached
// the bank index -> inherent 8-way conflicts, 2.5e7 measured; BK=64 rows =
// 128 B = full 32-bank stride + 3-bit chunk XOR measured ZERO in round 0).
// LDS: 2 buffers x (A 32K + B 32K) = 128 KiB.  Tile t in buf[t&1]; tile t+1's
// 8 loads issued in phases 0 (A x4) and 1 (B x4) into buf[t&1^1] (dead since
// end of tile t-1).  Sole loop wait: vmcnt(0) at tile tail -- last load has
// ~2.5 phases (~1000+ cyc) of lead, so this behaves as a counted wait.
// Phase = ds_read subtile [+ stage] -> barrier -> lgkmcnt(0)+sched_barrier
// (rule #18) -> setprio(1) -> 16 MFMA -> setprio(0) -> barrier.  B-frags
// (4n x 2kk = 32 VGPR) read once per K-tile (phases 0-1), held in registers.
__global__ __launch_bounds__(512, 2) void sl_gemm_bias(
    const unsigned short* __restrict__ A,   // xb bf16 [M,K]
    const unsigned short* __restrict__ B,   // W  bf16 [N,K]
    const float* __restrict__ bias,
    float* __restrict__ C) {
  extern __shared__ __align__(16) unsigned short lds[];
  unsigned short* As = lds;                    // 2 * A_ELEMS
  unsigned short* Bs = lds + 2 * A_ELEMS;      // 2 * B_ELEMS

  const int tid  = threadIdx.x;
  const int wave = tid >> 6;
  const int lane = tid & 63;

  // XCD-aware bijective swizzle (512 blocks, 8 XCDs, 64/chunk), nt fastest:
  // concurrent CUs of one XCD share A-panels in L2; B streams from L3
  // (96 MB working set < 256 MB L3).
  const int orig = blockIdx.y * (M_DIM / BM) + blockIdx.x;    // 0..511
  const int swz  = (orig & 7) * 64 + (orig >> 3);
  const int mt   = swz >> 4;                                  // 0..31
  const int nt   = swz & 15;                                  // 0..15
  const int m0 = mt * BM;
  const int n0 = nt * BN;

  // --- staging: thread covers row (tid>>3)+64r, phys 16B chunk tid&7 holds
  //     logical chunk (tid&7)^(row&7)  (pre-swizzled global source)
  const int srow = tid >> 3;                            // 0..63
  const int scol = ((tid & 7) ^ (srow & 7)) * 8;        // swizzled bf16 col
  const unsigned short* gA = A + (size_t)(m0 + srow) * K_DIM + scol;
  const unsigned short* gB = B + (size_t)(n0 + srow) * K_DIM + scol;
  const size_t GROW = (size_t)64 * K_DIM;   // 64 rows ahead (elems)
  const int ldsw = wave * 512;              // wave-uniform chunk base (elems)

  // --- fragment addressing (per-wave 128x64: 8 m-frags x 4 n-frags)
  const int wm   = (wave >> 2) * 128;
  const int wn   = (wave & 3) * 64;
  const int fm   = lane & 15;
  const int quad = lane >> 4;
  const int sw   = fm & 7;
  int offA[8], offB[4], pk[2];
#pragma unroll
  for (int i = 0; i < 8; ++i) offA[i] = (wm + i * 16 + fm) * BK;
#pragma unroll
  for (int j = 0; j < 4; ++j) offB[j] = (wn + j * 16 + fm) * BK;
#pragma unroll
  for (int kk = 0; kk < 2; ++kk) pk[kk] = ((kk * 4 + quad) ^ sw) * 8;

  f32x4 acc[8][4] = {};
  bf16x8 af[4][2], bf[4][2];

  // ---- prologue: stage tile 0 into buf0
#pragma unroll
  for (int r = 0; r < 4; ++r) {
    ASYNC16(gA + r * GROW, As + ldsw + r * 4096);
    ASYNC16(gB + r * GROW, Bs + ldsw + r * 4096);
  }
  gA += BK;
  gB += BK;
  asm volatile("s_waitcnt vmcnt(0)" ::: "memory");
  __builtin_amdgcn_sched_barrier(0);
  __builtin_amdgcn_s_barrier();

  int cur = 0;
  for (int t = 0; t < NT_TILES; ++t) {
    const unsigned short* Ac = As + cur * A_ELEMS;
    const unsigned short* Bc = Bs + cur * B_ELEMS;
    unsigned short* Asn = As + (cur ^ 1) * A_ELEMS + ldsw;
    unsigned short* Bsn = Bs + (cur ^ 1) * B_ELEMS + ldsw;
    const bool more = (t + 1 < NT_TILES);

    // ---- phase 0: m-half 0, n-half 0 (12 reads; stage A of t+1) ----------
#pragma unroll
    for (int i = 0; i < 4; ++i)
#pragma unroll
      for (int kk = 0; kk < 2; ++kk)
        af[i][kk] = *(const bf16x8*)(Ac + offA[i] + pk[kk]);
#pragma unroll
    for (int j = 0; j < 2; ++j)
#pragma unroll
      for (int kk = 0; kk < 2; ++kk)
        bf[j][kk] = *(const bf16x8*)(Bc + offB[j] + pk[kk]);
    if (more) {
#pragma unroll
      for (int r = 0; r < 4; ++r) ASYNC16(gA + r * GROW, Asn + r * 4096);
    }
    __builtin_amdgcn_sched_barrier(0);
    __builtin_amdgcn_s_barrier();
    asm volatile("s_waitcnt lgkmcnt(0)" ::: "memory");
    __builtin_amdgcn_sched_barrier(0);
    __builtin_amdgcn_s_setprio(1);
#pragma unroll
    for (int kk = 0; kk < 2; ++kk)
#pragma unroll
      for (int i = 0; i < 4; ++i)
#pragma unroll
        for (int j = 0; j < 2; ++j)
          acc[i][j] = __builtin_amdgcn_mfma_f32_16x16x32_bf16(
              af[i][kk], bf[j][kk], acc[i][j], 0, 0, 0);
    __builtin_amdgcn_s_setprio(0);
    __builtin_amdgcn_s_barrier();

    // ---- phase 1: m-half 0, n-half 1 (4 reads; stage B of t+1) -----------
#pragma unroll
    for (int j = 2; j < 4; ++j)
#pragma unroll
      for (int kk = 0; kk < 2; ++kk)
        bf[j][kk] = *(const bf16x8*)(Bc + offB[j] + pk[kk]);
    if (more) {
#pragma unroll
      for (int r = 0; r < 4; ++r) ASYNC16(gB + r * GROW, Bsn + r * 4096);
    }
    __builtin_amdgcn_sched_barrier(0);
    __builtin_amdgcn_s_barrier();
    asm volatile("s_waitcnt lgkmcnt(0)" ::: "memory");
    __builtin_amdgcn_sched_barrier(0);
    __builtin_amdgcn_s_setprio(1);
#pragma unroll
    for (int kk = 0; kk < 2; ++kk)
#pragma unroll
      for (int i = 0; i < 4; ++i)
#pragma unroll
        for (int j = 0; j < 2; ++j)
          acc[i][2 + j] = __builtin_amdgcn_mfma_f32_16x16x32_bf16(
              af[i][kk], bf[2 + j][kk], acc[i][2 + j], 0, 0, 0);
    __builtin_amdgcn_s_setprio(0);
    __builtin_amdgcn_s_barrier();

    // ---- phase 2: m-half 1, n-half 0 (8 reads) ---------------------------
#pragma unroll
    for (int i = 0; i < 4; ++i)
#pragma unroll
      for (int kk = 0; kk < 2; ++kk)
        af[i][kk] = *(const bf16x8*)(Ac + offA[4 + i] + pk[kk]);
    __builtin_amdgcn_sched_barrier(0);
    __builtin_amdgcn_s_barrier();
    asm volatile("s_waitcnt lgkmcnt(0)" ::: "memory");
    __builtin_amdgcn_sched_barrier(0);
    __builtin_amdgcn_s_setprio(1);
#pragma unroll
    for (int kk = 0; kk < 2; ++kk)
#pragma unroll
      for (int i = 0; i < 4; ++i)
#pragma unroll
        for (int j = 0; j < 2; ++j)
          acc[4 + i][j] = __builtin_amdgcn_mfma_f32_16x16x32_bf16(
              af[i][kk], bf[j][kk], acc[4 + i][j], 0, 0, 0);
    __builtin_amdgcn_s_setprio(0);
    __builtin_amdgcn_s_barrier();

    // ---- phase 3: m-half 1, n-half 1 (0 reads; tile-tail vmcnt drain) ----
    __builtin_amdgcn_s_setprio(1);
#pragma unroll
    for (int kk = 0; kk < 2; ++kk)
#pragma unroll
      for (int i = 0; i < 4; ++i)
#pragma unroll
        for (int j = 0; j < 2; ++j)
          acc[4 + i][2 + j] = __builtin_amdgcn_mfma_f32_16x16x32_bf16(
              af[i][kk], bf[2 + j][kk], acc[4 + i][2 + j], 0, 0, 0);
    __builtin_amdgcn_s_setprio(0);
    if (more) {
      asm volatile("s_waitcnt vmcnt(0)" ::: "memory");  // t+1's 8 loads landed
      __builtin_amdgcn_sched_barrier(0);
      gA += BK;
      gB += BK;
    }
    __builtin_amdgcn_s_barrier();

    cur ^= 1;
  }

  // --- epilogue: D row = A-index (quad*4+reg), col = B-index (lane&15)
  float bv[4];
#pragma unroll
  for (int tn = 0; tn < 4; ++tn) bv[tn] = bias[n0 + wn + tn * 16 + fm];

#pragma unroll
  for (int tm = 0; tm < 8; ++tm) {
    const int mbase = m0 + wm + tm * 16 + quad * 4;
#pragma unroll
    for (int tn = 0; tn < 4; ++tn) {
      const int n = n0 + wn + tn * 16 + fm;
      float* p = C + (size_t)mbase * N_DIM + n;
#pragma unroll
      for (int r = 0; r < 4; ++r)
        __builtin_nontemporal_store(acc[tm][tn][r] + bv[tn], p + (size_t)r * N_DIM);
    }
  }
}

// ---- fallback (only if workspace too small): naive fp32 SpMM ----------------
__global__ void sl_naive(const float* __restrict__ x, const float* __restrict__ vals,
                         const int* __restrict__ rows, const int* __restrict__ cols,
                         const float* __restrict__ bias, float* __restrict__ out,
                         int nnz) {
  const int o = blockIdx.x;
  int l = 0, h = nnz;
  while (l < h) { int m = (l + h) >> 1; if (rows[m] < o) l = m + 1; else h = m; }
  const int s = l;
  h = nnz;
  while (l < h) { int m = (l + h) >> 1; if (rows[m] <= o) l = m + 1; else h = m; }
  const int e = l;
  const float bv = bias[o];
  for (int b = threadIdx.x; b < M_DIM; b += blockDim.x) {
    float acc = bv;
    const float* xb = x + (size_t)b * K_DIM;
    for (int k = s; k < e; ++k) acc += vals[k] * xb[cols[k]];
    out[(size_t)b * N_DIM + o] = acc;
  }
}

extern "C" void kernel_launch(void* const* d_in, const int* in_sizes, int n_in,
                              void* d_out, int out_size, void* d_ws, size_t ws_size,
                              hipStream_t stream) {
  const float* x    = (const float*)d_in[0];
  const float* vals = (const float*)d_in[1];
  const int*   rows = (const int*)d_in[2];
  const int*   cols = (const int*)d_in[3];
  const float* bias = (const float*)d_in[4];
  float* out = (float*)d_out;
  const int nnz = in_sizes[1];

  const size_t xb_bytes = (size_t)M_DIM * K_DIM * 2;  // 64 MiB
  const size_t w_bytes  = (size_t)N_DIM * K_DIM * 2;  // 32 MiB
  const int cvt_blocks  = (M_DIM * K_DIM) / 8 / 256;  // 16384

  if (ws_size >= xb_bytes + w_bytes) {
    unsigned short* xb = (unsigned short*)d_ws;
    unsigned short* W  = (unsigned short*)((char*)d_ws + xb_bytes);

    static bool attr_done = false;
    if (!attr_done) {
      (void)hipFuncSetAttribute((const void*)sl_gemm_bias,
                                hipFuncAttributeMaxDynamicSharedMemorySize,
                                LDS_BYTES);
      attr_done = true;
    }

    sl_prep_bs<<<N_DIM + cvt_blocks, 256, 0, stream>>>(
        (const float4*)x, (u16x8*)xb, vals, rows, cols, W, nnz);
    sl_gemm_bias<<<dim3(M_DIM / BM, N_DIM / BN), 512, LDS_BYTES, stream>>>(
        xb, W, bias, out);
  } else {
    sl_naive<<<N_DIM, 256, 0, stream>>>(x, vals, rows, cols, bias, out, nnz);
  }
}